// Round 3
// baseline (90.647 us; speedup 1.0000x reference)
//
#include <hip/hip_runtime.h>
#include <cfloat>

// Problem constants (match reference setup_inputs)
#define BB 4
#define NQ 8192
#define NK 2048
#define CC 128
#define C4 (CC / 4)            // 32 float4 per feature row

#define QPB 64                 // queries per block (= lane id)
#define SPLITS 16              // key splits, one wave each (wave-uniform)
#define KPS (NK / SPLITS)      // 128 keys per split (local idx fits 7 bits)
#define NTHR (QPB * SPLITS)    // 1024 threads per block

// ---------------------------------------------------------------------------
// Fused: kNN (branchless packed top-4 per split via v_med3) + IDW interp.
//   grid = (NQ/QPB, BB) = (128,4) = 512 blocks -> 2 blocks/CU = 32 waves/CU
//   Round-3 probe: NO LDS in the scan. Key coords are wave-uniform per
//   split, so they are read through uniform (scalar-cache, s_load) loads
//   directly from global memory. If the round-0/2 kernels were bound by
//   the ds_read->lgkmcnt->use interlock, this removes it entirely.
// ---------------------------------------------------------------------------
__global__ __launch_bounds__(NTHR, 8) void fp_fused(
    const float*  __restrict__ xyz_q,
    const float*  __restrict__ xyz_k,
    const float4* __restrict__ vk,
    float4*       __restrict__ out)
{
    __shared__ unsigned rd[SPLITS][4][QPB];   // 16 KiB: packed fp32 cands
    __shared__ float sw[QPB][4];              // 1 KiB
    __shared__ int   si[QPB][4];              // 1 KiB

    const int b     = blockIdx.y;
    const int qbase = blockIdx.x * QPB;
    const int tid   = threadIdx.x;
    const int lane  = tid & 63;               // query within block
    const int split = tid >> 6;               // wave id == key split (uniform)
    const int q     = qbase + lane;

    const float qx = xyz_q[(b * NQ + q) * 3 + 0];
    const float qy = xyz_q[(b * NQ + q) * 3 + 1];
    const float qz = xyz_q[(b * NQ + q) * 3 + 2];

    // wave-uniform key range; uniform base pointer for scalar loads
    const int kbeg = __builtin_amdgcn_readfirstlane(split * KPS);
    const float* __restrict__ kb = xyz_k + ((size_t)b * NK + kbeg) * 3;

    // ---- phase 1: branchless fp32 scan, packed top-4 via med3 insert ----
    // keys via wave-uniform loads (scalar cache); (k-q)^2 == (q-k)^2 bitwise
    // invariant: u0 <= u1 <= u2 <= u3, low 7 bits = local key index
    float u0 = FLT_MAX, u1 = FLT_MAX, u2 = FLT_MAX, u3 = FLT_MAX;

    #pragma unroll 4
    for (int j = 0; j < KPS; ++j) {
        float kx = kb[j * 3 + 0];             // uniform addr -> s_load
        float ky = kb[j * 3 + 1];
        float kz = kb[j * 3 + 2];
        float dx = kx - qx, dy = ky - qy, dz = kz - qz;
        float t = fmaf(dx, dx, fmaf(dy, dy, dz * dz));   // >= 0 structurally
        float p = __uint_as_float((__float_as_uint(t) & 0xFFFFFF80u) | (unsigned)j);
        u3 = __builtin_amdgcn_fmed3f(p, u2, u3);
        u2 = __builtin_amdgcn_fmed3f(p, u1, u2);
        u1 = __builtin_amdgcn_fmed3f(p, u0, u1);
        u0 = fminf(u0, p);
    }

    // ---- phase 2a: store packed fp32 candidates (lane-contiguous b32) ----
    rd[split][0][lane] = __float_as_uint(u0);
    rd[split][1][lane] = __float_as_uint(u1);
    rd[split][2][lane] = __float_as_uint(u2);
    rd[split][3][lane] = __float_as_uint(u3);
    __syncthreads();

    // ---- phase 2b: wave 0 selects global top-4, refines in fp64, picks 3 --
    if (tid < QPB) {
        // convert packed fp32 -> fp64 with 11-bit global idx in low bits
        // (cvt_f64_f32 leaves low 29 mantissa bits zero); float order preserved
        double m0 = DBL_MAX, m1 = DBL_MAX, m2 = DBL_MAX, m3 = DBL_MAX;
        #pragma unroll 4
        for (int s = 0; s < SPLITS; ++s) {
            #pragma unroll
            for (int c = 0; c < 4; ++c) {
                unsigned pb = rd[s][c][tid];
                float vf = __uint_as_float(pb & 0xFFFFFF80u);
                unsigned long long gidx =
                    (unsigned long long)(s * KPS) + (pb & 0x7Fu);
                unsigned long long xb =
                    (unsigned long long)__double_as_longlong((double)vf) | gidx;
                double x = __longlong_as_double((long long)xb);
                m3 = fmin(m3, fmax(x, m2));
                m2 = fmin(m2, fmax(x, m1));
                m1 = fmin(m1, fmax(x, m0));
                m0 = fmin(m0, x);
            }
        }

        // fp64-exact refine of the 4 survivors (keys re-read from global;
        // 64 threads x 4 keys, L1/L2-hot)
        double d0, d1, d2, d3;
        int    i0, i1, i2, i3;
        {
            unsigned long long mb[4] = {
                (unsigned long long)__double_as_longlong(m0),
                (unsigned long long)__double_as_longlong(m1),
                (unsigned long long)__double_as_longlong(m2),
                (unsigned long long)__double_as_longlong(m3)
            };
            double dd[4]; int ii[4];
            #pragma unroll
            for (int c = 0; c < 4; ++c) {
                int kidx = (int)(mb[c] & 0x7FFull);
                const float* kp = xyz_k + ((size_t)b * NK + kidx) * 3;
                double dx = (double)qx - (double)kp[0];
                double dy = (double)qy - (double)kp[1];
                double dz = (double)qz - (double)kp[2];
                dd[c] = dx * dx + dy * dy + dz * dz;   // exact for fp32 inputs
                ii[c] = kidx;
            }
            d0 = dd[0]; d1 = dd[1]; d2 = dd[2]; d3 = dd[3];
            i0 = ii[0]; i1 = ii[1]; i2 = ii[2]; i3 = ii[3];
        }

        // sort-4 network (ascending), keep smallest 3
        #define CSW(da, db, ia, ib)                                     \
            { bool c_ = (da) > (db);                                    \
              double dt_ = c_ ? (db) : (da); (db) = c_ ? (da) : (db);   \
              (da) = dt_;                                               \
              int it_ = c_ ? (ib) : (ia); (ib) = c_ ? (ia) : (ib);      \
              (ia) = it_; }
        CSW(d0, d1, i0, i1);
        CSW(d2, d3, i2, i3);
        CSW(d0, d2, i0, i2);
        CSW(d1, d3, i1, i3);
        CSW(d1, d2, i1, i2);
        #undef CSW

        double e0 = fmax(d0, 1e-10);
        double e1 = fmax(d1, 1e-10);
        double e2 = fmax(d2, 1e-10);
        double w0 = 1.0 / e0, w1 = 1.0 / e1, w2 = 1.0 / e2;
        double s  = w0 + w1 + w2;
        sw[tid][0] = (float)(w0 / s);
        sw[tid][1] = (float)(w1 / s);
        sw[tid][2] = (float)(w2 / s);
        si[tid][0] = i0;
        si[tid][1] = i1;
        si[tid][2] = i2;
    }
    __syncthreads();

    // ---- phase 3: gather + weighted sum, coalesced float4 writes ----
    const float4* vb = vk + (size_t)b * NK * C4;
    float4* ob = out + ((size_t)b * NQ + qbase) * C4;
    #pragma unroll
    for (int r = 0; r < (QPB * C4) / NTHR; ++r) {   // 2 iters
        int o  = r * NTHR + tid;
        int qq = o >> 5;          // C4 = 32 float4 per query
        int c4 = o & (C4 - 1);
        float w0 = sw[qq][0], w1 = sw[qq][1], w2 = sw[qq][2];
        int   j0 = si[qq][0], j1 = si[qq][1], j2 = si[qq][2];
        float4 v0 = vb[j0 * C4 + c4];
        float4 v1 = vb[j1 * C4 + c4];
        float4 v2 = vb[j2 * C4 + c4];
        float4 res;
        res.x = fmaf(w0, v0.x, fmaf(w1, v1.x, w2 * v2.x));
        res.y = fmaf(w0, v0.y, fmaf(w1, v1.y, w2 * v2.y));
        res.z = fmaf(w0, v0.z, fmaf(w1, v1.z, w2 * v2.z));
        res.w = fmaf(w0, v0.w, fmaf(w1, v1.w, w2 * v2.w));
        ob[o] = res;
    }
}

// ---------------------------------------------------------------------------
extern "C" void kernel_launch(void* const* d_in, const int* in_sizes, int n_in,
                              void* d_out, int out_size, void* d_ws, size_t ws_size,
                              hipStream_t stream)
{
    const float* xyz_q = (const float*)d_in[0];
    const float* xyz_k = (const float*)d_in[1];
    const float* v_k   = (const float*)d_in[2];

    fp_fused<<<dim3(NQ / QPB, BB), dim3(NTHR), 0, stream>>>(
        xyz_q, xyz_k, (const float4*)v_k, (float4*)d_out);
}